// Round 3
// baseline (201.524 us; speedup 1.0000x reference)
//
#include <hip/hip_runtime.h>
#include <math.h>

#define Bb 8
#define Cc 128
#define Nn 3136                  // 56*56 real spatial
#define Np 3200                  // padded spatial (50 x 64)
#define NT 50                    // 64-row tiles per batch
#define Mm (Bb*Cc*Nn)            // elements per output tensor
#define L2E 1.44269504088896340736f
#define C44 (44.0f * L2E)        // shift 44 in log2 domain

// xt2: [b][T(50)][seg(16)][row(64)][8 u16]   seg = channel-chunk of 8
#define XT2B (NT*16*64*8)        // 409600 u16 per batch
// xc2: [b][T(50)][seg(8)][c(128)][8 u16]     seg = i-chunk of 8
#define XC2B (NT*8*128*8)        // 409600 u16 per batch

typedef unsigned short u16;
typedef unsigned int   u32;
typedef __attribute__((ext_vector_type(8)))  u16      u16x8;
typedef __attribute__((ext_vector_type(8)))  _Float16 f16x8;
typedef __attribute__((ext_vector_type(2)))  _Float16 f16x2;
typedef __attribute__((ext_vector_type(4)))  u32      u32x4;
typedef __attribute__((ext_vector_type(4)))  float    f32x4;
typedef __attribute__((ext_vector_type(16))) float    f32x16;

__device__ __forceinline__ float exp2fast(float x) {
#if __has_builtin(__builtin_amdgcn_exp2f)
    return __builtin_amdgcn_exp2f(x);
#else
    float r; asm("v_exp_f32 %0, %1" : "=v"(r) : "v"(x)); return r;
#endif
}

// ---------------------------------------------------------------------------
// Prep: x f32 -> fragment-major fp16 tiles xt2/xc2 (all later MFMA fragment
// loads are perfectly coalesced global loads). Slot3 = gamma. x-copy moved
// to finish_kernel (slot2 is now a partial-PV scratch slot).
// grid 400 = 8 b * 50 n-blocks; nblk 49 zero-pads tile 49.
// ---------------------------------------------------------------------------
__global__ __launch_bounds__(256) void prep_kernel(const float* __restrict__ x,
                                                   const float* __restrict__ gamma_p,
                                                   float* __restrict__ out,
                                                   u16* __restrict__ xt2,
                                                   u16* __restrict__ xc2,
                                                   float* __restrict__ row_d) {
    const int bx = blockIdx.x;
    const int b = bx / 50, nblk = bx % 50;
    const int t = threadIdx.x;

    if (nblk == 49) {            // pad tile: rows 3136..3199 all zero
        const u16x8 z8 = {0, 0, 0, 0, 0, 0, 0, 0};
        u16* dt = xt2 + ((size_t)b * NT + 49) * (16 * 64 * 8);
        u16* dc = xc2 + ((size_t)b * NT + 49) * (8 * 128 * 8);
        #pragma unroll
        for (int it = 0; it < 4; ++it) {
            *(u16x8*)&dt[(it * 256 + t) * 8] = z8;
            *(u16x8*)&dc[(it * 256 + t) * 8] = z8;
        }
        if (t < 64) row_d[b * Np + Nn + t] = 1.0f;   // pad denominators: 1
        return;
    }

    __shared__ float lx[Cc][65];
    const int n0 = nblk * 64;

    // phase 1: coalesced read
    #pragma unroll 8
    for (int r = 0; r < 32; ++r) {
        const int c = r * 4 + (t >> 6);
        const int g = (b * Cc + c) * Nn + n0 + (t & 63);
        lx[c][t & 63] = x[g];
    }
    __syncthreads();

    // phase 2: xt2 — thread (row nl, cseg) -> segs cseg*4+k, fully coalesced
    {
        const int nl = t & 63, cseg = t >> 6;
        u16x8 hv[4];
        #pragma unroll
        for (int cc = 0; cc < 32; ++cc) {
            const _Float16 hh = (_Float16)lx[cseg * 32 + cc][nl];
            hv[cc >> 3][cc & 7] = __builtin_bit_cast(u16, hh);
        }
        u16* base = xt2 + (((size_t)(b * NT + nblk) * 16 + cseg * 4) * 64 + nl) * 8;
        #pragma unroll
        for (int k = 0; k < 4; ++k) *(u16x8*)&base[k * (64 * 8)] = hv[k];
    }
    // phase 2b: xc2 — thread (c, half) -> segs half*4+k
    {
        const int c = t >> 1, half = t & 1;
        u16x8 hv[4];
        #pragma unroll
        for (int k = 0; k < 32; ++k) {
            const _Float16 hh = (_Float16)lx[c][half * 32 + k];
            hv[k >> 3][k & 7] = __builtin_bit_cast(u16, hh);
        }
        u16* base = xc2 + (((size_t)(b * NT + nblk) * 8 + half * 4) * 128 + c) * 8;
        #pragma unroll
        for (int k = 0; k < 4; ++k) *(u16x8*)&base[k * (128 * 8)] = hv[k];
    }
    if (bx == 0 && t == 0) out[(size_t)3 * Mm] = gamma_p[0];
}

// ---------------------------------------------------------------------------
// Stats: row_d[b,i] += sum_j exp(e_ij - 44). No LDS, no barriers; dual MFMA
// chains + next-tile register prefetch (A for jt+1 issued before jt's MFMAs;
// compiler emits counted vmcnt so the prefetch stays in flight).
// grid 1568 = 49 i-blocks * 4 j-quarters * 8 b (b = bx&7 -> XCD-pinned L2).
// ---------------------------------------------------------------------------
__global__ __launch_bounds__(256, 3) void stats_kernel(const u16* __restrict__ xt2,
                                                       float* __restrict__ row_d) {
    const int bx = blockIdx.x;
    const int b = bx & 7, rem = bx >> 3;
    const int i0t = rem >> 2, jq = rem & 3;      // i-tile 0..48
    const int t = threadIdx.x;
    const int w = t >> 6, l = t & 63, lane = l & 31, h = l >> 5;
    const int igrp = w & 1, jsub = w >> 1;
    const u16* __restrict__ xb = xt2 + (size_t)b * XT2B;

    f16x8 Bf[8];                                 // resident i-row fragments
    const int irow = igrp * 32 + lane;
    #pragma unroll
    for (int kk = 0; kk < 8; ++kk)
        Bf[kk] = *(const f16x8*)&xb[(((size_t)i0t * 16 + 2 * kk + h) * 64 + irow) * 8];

    const int jt0 = jq * 12 + (jq < 2 ? jq : 2); // 0, 13, 26, 38
    const int jcnt = 12 + (jq < 2 ? 1 : 0);      // 13, 13, 12, 12
    const int jrow = jsub * 32 + lane;

    f16x8 Ac[8], An[8];                          // cur/next A-tile fragments
    {
        const u16* ab = &xb[((size_t)jt0 * 16 * 64 + jrow) * 8];
        #pragma unroll
        for (int kk = 0; kk < 8; ++kk)
            Ac[kk] = *(const f16x8*)&ab[(2 * kk + h) * 512];
    }

    float sa = 0.f, sb = 0.f;
    for (int jt = jt0; jt < jt0 + jcnt; ++jt) {
        const int tn = (jt + 1 < jt0 + jcnt) ? jt + 1 : jt;
        const u16* an = &xb[((size_t)tn * 16 * 64 + jrow) * 8];
        #pragma unroll
        for (int kk = 0; kk < 8; ++kk)           // prefetch next tile (in flight)
            An[kk] = *(const f16x8*)&an[(2 * kk + h) * 512];

        f32x16 ea, eb;
        #pragma unroll
        for (int r = 0; r < 16; ++r) { ea[r] = 0.f; eb[r] = 0.f; }
        __builtin_amdgcn_s_setprio(1);
        #pragma unroll
        for (int kk = 0; kk < 4; ++kk) {
            ea = __builtin_amdgcn_mfma_f32_32x32x16_f16(Ac[2 * kk],     Bf[2 * kk],     ea, 0, 0, 0);
            eb = __builtin_amdgcn_mfma_f32_32x32x16_f16(Ac[2 * kk + 1], Bf[2 * kk + 1], eb, 0, 0, 0);
        }
        __builtin_amdgcn_s_setprio(0);

        if (jt == i0t) {                          // diagonal tile: masked path
            const bool dsub = (jsub == igrp);
            #pragma unroll
            for (int r = 0; r < 16; ++r) {
                const int mrow = (r & 3) + 8 * (r >> 2) + 4 * h;
                float v = ea[r] + eb[r];
                if (dsub && mrow == lane) v = 0.f;
                const float e = exp2fast(fmaf(v, L2E, -C44));
                if (r & 1) sb += e; else sa += e;
            }
        } else {
            #pragma unroll
            for (int r = 0; r < 16; ++r) {
                const float e = exp2fast(fmaf(ea[r] + eb[r], L2E, -C44));
                if (r & 1) sb += e; else sa += e;
            }
        }
        #pragma unroll
        for (int kk = 0; kk < 8; ++kk) Ac[kk] = An[kk];
    }
    float ssum = sa + sb;
    ssum += __shfl_xor(ssum, 32, 64);   // combine h-halves (disjoint j-rows)
    if (h == 0) atomicAdd(&row_d[b * Np + i0t * 64 + igrp * 32 + lane], ssum);
}

// ---------------------------------------------------------------------------
// Conv: row_d -> c_i = 44*log2e + log2(d_i), so P = exp2(e*log2e - c_i).
// ---------------------------------------------------------------------------
__global__ __launch_bounds__(256) void conv_kernel(float* __restrict__ row_d) {
    const int i = blockIdx.x * 256 + threadIdx.x;
    row_d[i] = C44 + __log2f(row_d[i]);
}

// ---------------------------------------------------------------------------
// Out v3: BARRIER-FREE main loop. Wave (isub,jgrp) computes energy quadrant
// D[m=i(isub-half)][n=j(jgrp-half)], keeps P IN REGISTERS (cvt_pkrtz pairs +
// one shfl_xor(32) half-swap reassemble exact B-frags: frag(kt) elem e maps
// to P-row kt*16+h*8+e; owner half = (e>>2), owner quad = 2kt+h), then
// accumulates PV for ALL 128 c over its own K-half (K-split by isub).
// Epilogue: single barrier, LDS combine of isub pairs, store raw partials.
// grid 1176 = 8 b * 49 j * 3 i-thirds (17/17/16 of 50 tiles) -> slots 0/1/2.
// ---------------------------------------------------------------------------
__global__ __launch_bounds__(256, 2) void out_kernel(const u16* __restrict__ xt2,
                                                     const u16* __restrict__ xc2,
                                                     const float* __restrict__ row_c,
                                                     float* __restrict__ out) {
    __shared__ float sred[2][4][16][64];         // 32768 B, epilogue only

    const int bx = blockIdx.x;
    const int b = bx & 7, rem = bx >> 3;         // rem 0..146
    const int j0t = rem / 3, q = rem % 3;        // j-tile 0..48, i-third
    const int ti0 = (q == 0) ? 0 : (q == 1 ? 17 : 34);
    const int ti1 = (q == 0) ? 17 : (q == 1 ? 34 : 50);
    const int t = threadIdx.x;
    const int w = t >> 6, l = t & 63, lane = l & 31, h = l >> 5;
    const int isub = w & 1, jgrp = w >> 1;
    const u16* __restrict__ xtb = xt2 + (size_t)b * XT2B;
    const u16* __restrict__ xcb = xc2 + (size_t)b * XC2B;

    f16x8 Bj[8];                                 // resident j-row fragments
    const int jrow = jgrp * 32 + lane;
    #pragma unroll
    for (int kk = 0; kk < 8; ++kk)
        Bj[kk] = *(const f16x8*)&xtb[(((size_t)j0t * 16 + 2 * kk + h) * 64 + jrow) * 8];

    f32x16 acc[4];                               // PV partials: 4 c-tiles x 16
    #pragma unroll
    for (int ct = 0; ct < 4; ++ct)
        #pragma unroll
        for (int r = 0; r < 16; ++r) acc[ct][r] = 0.f;

    const int arow = isub * 32 + lane;

    for (int ti = ti0; ti < ti1; ++ti) {
        // issue all fragment loads first; prev-iter PV MFMAs cover latency
        f16x8 Ae[8];
        const u16* ab = &xtb[((size_t)ti * 16 * 64 + arow) * 8];
        #pragma unroll
        for (int kk = 0; kk < 8; ++kk)
            Ae[kk] = *(const f16x8*)&ab[(2 * kk + h) * 512];

        f16x8 Av[4][2];                          // V frags, K-half = isub
        const u16* vb = &xcb[((size_t)(ti * 8 + isub * 4 + h) * 128 + lane) * 8];
        #pragma unroll
        for (int ct = 0; ct < 4; ++ct)
            #pragma unroll
            for (int kt = 0; kt < 2; ++kt)
                Av[ct][kt] = *(const f16x8*)&vb[kt * 2 * 1024 + ct * 256];

        // energy: D[m=i32][n=j32], K=128
        f32x16 ea;
        #pragma unroll
        for (int r = 0; r < 16; ++r) ea[r] = 0.f;
        __builtin_amdgcn_s_setprio(1);
        #pragma unroll
        for (int kk = 0; kk < 8; ++kk)
            ea = __builtin_amdgcn_mfma_f32_32x32x16_f16(Ae[kk], Bj[kk], ea, 0, 0, 0);
        __builtin_amdgcn_s_setprio(0);

        // P = exp2(e*l2e - c_i), f16-pack quads, half-exchange via shfl
        const float* cb = &row_c[b * Np + ti * 64 + isub * 32];
        const bool dt = (ti == j0t) && (isub == jgrp);
        u32 pk[4][2], sw[4][2];
        #pragma unroll
        for (int qq = 0; qq < 4; ++qq) {
            const f32x4 cv = *(const f32x4*)&cb[qq * 8 + h * 4];
            float pv[4];
            #pragma unroll
            for (int r2 = 0; r2 < 4; ++r2) {
                const int m = qq * 8 + h * 4 + r2;
                float v = ea[qq * 4 + r2];
                if (dt && m == lane) v = 0.f;
                pv[r2] = exp2fast(fmaf(v, L2E, -cv[r2]));
            }
            pk[qq][0] = __builtin_bit_cast(u32, __builtin_amdgcn_cvt_pkrtz(pv[0], pv[1]));
            pk[qq][1] = __builtin_bit_cast(u32, __builtin_amdgcn_cvt_pkrtz(pv[2], pv[3]));
            sw[qq][0] = __shfl_xor(pk[qq][0], 32, 64);
            sw[qq][1] = __shfl_xor(pk[qq][1], 32, 64);
        }
        f16x8 Bp[2];
        #pragma unroll
        for (int kt = 0; kt < 2; ++kt) {         // static indices; h via cndmask
            u32x4 bw;
            bw[0] = h ? sw[2 * kt + 1][0] : pk[2 * kt][0];
            bw[1] = h ? sw[2 * kt + 1][1] : pk[2 * kt][1];
            bw[2] = h ? pk[2 * kt + 1][0] : sw[2 * kt][0];
            bw[3] = h ? pk[2 * kt + 1][1] : sw[2 * kt][1];
            Bp[kt] = __builtin_bit_cast(f16x8, bw);
        }

        // PV: D[m=c][n=j], K = isub's 32 (combined at epilogue)
        __builtin_amdgcn_s_setprio(1);
        #pragma unroll
        for (int ct = 0; ct < 4; ++ct)
            #pragma unroll
            for (int kt = 0; kt < 2; ++kt)
                acc[ct] = __builtin_amdgcn_mfma_f32_32x32x16_f16(Av[ct][kt], Bp[kt], acc[ct], 0, 0, 0);
        __builtin_amdgcn_s_setprio(0);
    }

    // epilogue: combine isub pairs via LDS (the only barrier in the kernel)
    if (isub == 1) {
        #pragma unroll
        for (int ct = 0; ct < 4; ++ct)
            #pragma unroll
            for (int r = 0; r < 16; ++r)
                sred[jgrp][ct][r][l] = acc[ct][r];
    }
    __syncthreads();
    if (isub == 0) {
        const int jj = j0t * 64 + jgrp * 32 + lane;
        #pragma unroll
        for (int ct = 0; ct < 4; ++ct) {
            #pragma unroll
            for (int r = 0; r < 16; ++r) {
                const int mrow = (r & 3) + 8 * (r >> 2) + 4 * h;
                const float v = acc[ct][r] + sred[jgrp][ct][r][l];
                out[(size_t)q * Mm + (size_t)(b * Cc + ct * 32 + mrow) * Nn + jj] = v;
            }
        }
    }
}

// ---------------------------------------------------------------------------
// Finish: o = relu(p0+p1+p2); slot0 = gamma*o + x; slot1 = o; slot2 = x.
// Pure streaming: 51.4 MB read + 38.6 MB write.
// ---------------------------------------------------------------------------
__global__ __launch_bounds__(256) void finish_kernel(const float* __restrict__ x,
                                                     const float* __restrict__ gamma_p,
                                                     float* __restrict__ out) {
    const float gamma = gamma_p[0];
    const size_t base = ((size_t)blockIdx.x * 256 + threadIdx.x) * 4;
    const f32x4 pa = *(const f32x4*)&out[base];
    const f32x4 pb = *(const f32x4*)&out[(size_t)Mm + base];
    const f32x4 pc = *(const f32x4*)&out[(size_t)2 * Mm + base];
    const f32x4 xv = *(const f32x4*)&x[base];
    f32x4 yo, oo;
    #pragma unroll
    for (int r = 0; r < 4; ++r) {
        const float o = fmaxf(pa[r] + pb[r] + pc[r], 0.0f);
        oo[r] = o;
        yo[r] = fmaf(gamma, o, xv[r]);
    }
    *(f32x4*)&out[base] = yo;
    *(f32x4*)&out[(size_t)Mm + base] = oo;
    *(f32x4*)&out[(size_t)2 * Mm + base] = xv;
}

extern "C" void kernel_launch(void* const* d_in, const int* in_sizes, int n_in,
                              void* d_out, int out_size, void* d_ws, size_t ws_size,
                              hipStream_t stream) {
    const float* x       = (const float*)d_in[0];
    const float* gamma_p = (const float*)d_in[1];
    float* out = (float*)d_out;

    // ws layout (~12.6 MB): row_d (8x3200 f32, 128K reserved) | xt2 | xc2
    float* row_d = (float*)d_ws;
    u16* xt2 = (u16*)((char*)d_ws + (1 << 17));
    u16* xc2 = xt2 + (size_t)Bb * XT2B;

    hipMemsetAsync(row_d, 0, (size_t)Bb * Np * sizeof(float), stream);
    prep_kernel  <<<400, 256, 0, stream>>>(x, gamma_p, out, xt2, xc2, row_d);
    stats_kernel <<<1568, 256, 0, stream>>>(xt2, row_d);
    conv_kernel  <<<100, 256, 0, stream>>>(row_d);
    out_kernel   <<<1176, 256, 0, stream>>>(xt2, xc2, row_d, out);
    finish_kernel<<<3136, 256, 0, stream>>>(x, gamma_p, out);
}